// Round 2
// baseline (393.991 us; speedup 1.0000x reference)
//
#include <hip/hip_runtime.h>

// ShiftingLayer: out = zeros(H,W); out[i + trunc(wr[i,j]), j + trunc(wc[i,j])] = x[i,j]
// (out-of-bounds target -> dropped). H=4096, W=8192, fp32.
//
// Memory-bound: 3 x 128 MiB reads + 2 x 128 MiB writes (zero-init + scatter).
// Fast path: when all 4 shifts of a thread's float4-chunk are zero (the bench
// inputs: weights are zero-initialized), the store is a coalesced aligned
// float4 to the identity location.

constexpr int H = 4096;
constexpr int W = 8192;          // 2^13
constexpr long long TOTAL = (long long)H * W;

// Zero-init d_out (poisoned to 0xAA before every timed launch).
// Done as a kernel rather than hipMemsetAsync to keep the captured graph
// kernel-only (most robust under graph capture).
__global__ __launch_bounds__(256) void zero_out_kernel(float4* __restrict__ out) {
    long long tid = (long long)blockIdx.x * blockDim.x + threadIdx.x;
    out[tid] = make_float4(0.f, 0.f, 0.f, 0.f);
}

__global__ __launch_bounds__(256) void shift_scatter_kernel(
    const float* __restrict__ x,
    const float* __restrict__ wr,
    const float* __restrict__ wc,
    float* __restrict__ out)
{
    long long tid  = (long long)blockIdx.x * blockDim.x + threadIdx.x;
    long long base = tid * 4;                 // flat index of first of 4 elems
    // grid sized exactly: TOTAL/4 threads, no bounds check needed

    int row = (int)(base >> 13);              // base / W
    int col = (int)(base & (W - 1));          // base % W  (multiple of 4)

    const float4 xv = *reinterpret_cast<const float4*>(x  + base);
    const float4 rv = *reinterpret_cast<const float4*>(wr + base);
    const float4 cv = *reinterpret_cast<const float4*>(wc + base);

    // C cast float->int truncates toward zero == jnp.trunc + astype(int32)
    int rs0 = (int)rv.x, rs1 = (int)rv.y, rs2 = (int)rv.z, rs3 = (int)rv.w;
    int cs0 = (int)cv.x, cs1 = (int)cv.y, cs2 = (int)cv.z, cs3 = (int)cv.w;

    // Fast path: all shifts zero -> identity placement, aligned float4 store.
    if (((rs0 | rs1 | rs2 | rs3) | (cs0 | cs1 | cs2 | cs3)) == 0) {
        *reinterpret_cast<float4*>(out + base) = xv;
        return;
    }

    // General path: per-element bounds-checked scatter (mode="drop").
    int tr, tc;
    tr = row + rs0; tc = col + 0 + cs0;
    if ((unsigned)tr < (unsigned)H && (unsigned)tc < (unsigned)W)
        out[(long long)tr * W + tc] = xv.x;
    tr = row + rs1; tc = col + 1 + cs1;
    if ((unsigned)tr < (unsigned)H && (unsigned)tc < (unsigned)W)
        out[(long long)tr * W + tc] = xv.y;
    tr = row + rs2; tc = col + 2 + cs2;
    if ((unsigned)tr < (unsigned)H && (unsigned)tc < (unsigned)W)
        out[(long long)tr * W + tc] = xv.z;
    tr = row + rs3; tc = col + 3 + cs3;
    if ((unsigned)tr < (unsigned)H && (unsigned)tc < (unsigned)W)
        out[(long long)tr * W + tc] = xv.w;
}

extern "C" void kernel_launch(void* const* d_in, const int* in_sizes, int n_in,
                              void* d_out, int out_size, void* d_ws, size_t ws_size,
                              hipStream_t stream) {
    const float* x  = (const float*)d_in[0];
    const float* wr = (const float*)d_in[1];
    const float* wc = (const float*)d_in[2];
    float* out = (float*)d_out;

    const int block = 256;
    const long long threads = TOTAL / 4;            // 8,388,608 float4 chunks
    const int grid = (int)(threads / block);        // 32,768 blocks

    zero_out_kernel<<<grid, block, 0, stream>>>((float4*)out);
    shift_scatter_kernel<<<grid, block, 0, stream>>>(x, wr, wc, out);
}

// Round 4
// 392.812 us; speedup vs baseline: 1.0030x; 1.0030x over previous
//
#include <hip/hip_runtime.h>

// ShiftingLayer: out = zeros(H,W); out[i + trunc(wr[i,j]), j + trunc(wc[i,j])] = x[i,j]
// (OOB targets dropped). H=4096, W=8192, fp32.
//
// Single-pass formulation (general-correct):
//   Pass A (fused_place): each thread owns a float4 chunk. Writes, at its own
//     location, x where that element's shift is zero, 0 where it isn't. Any
//     chunk with a nonzero shift is appended to a worklist in d_ws.
//   Pass B (worklist_scatter): scatters only nonzero-shift elements (stream
//     order after pass A; duplicate-target winners are unspecified in JAX so
//     overwrites are legal). Bench inputs (zero weights) -> empty worklist.
// Removes the 128 MiB dedicated zero pass: 768 -> 512 MiB total traffic.

constexpr int H = 4096;
constexpr int W = 8192;                         // 2^13
constexpr long long TOTAL  = (long long)H * W;  // 33,554,432
constexpr long long NCHUNK = TOTAL / 4;         // 8,388,608 float4 chunks

// native clang vector type — accepted by __builtin_nontemporal_store
typedef float vf4 __attribute__((ext_vector_type(4)));

// ---- worklist path -------------------------------------------------------

__global__ __launch_bounds__(64) void init_ws_kernel(unsigned* __restrict__ ws) {
    if (threadIdx.x == 0) ws[0] = 0u;           // d_ws is poisoned 0xAA each call
}

__global__ __launch_bounds__(256) void fused_place_kernel(
    const float* __restrict__ x,
    const float* __restrict__ wr,
    const float* __restrict__ wc,
    float* __restrict__ out,
    unsigned* __restrict__ ws_count,
    unsigned* __restrict__ ws_list)
{
    long long tid  = (long long)blockIdx.x * blockDim.x + threadIdx.x;
    long long base = tid * 4;                   // exact grid: no bounds check

    const vf4 xv = *reinterpret_cast<const vf4*>(x  + base);
    const vf4 rv = *reinterpret_cast<const vf4*>(wr + base);
    const vf4 cv = *reinterpret_cast<const vf4*>(wc + base);

    // C float->int cast truncates toward zero == jnp.trunc + astype(int32)
    int rs0 = (int)rv.x, rs1 = (int)rv.y, rs2 = (int)rv.z, rs3 = (int)rv.w;
    int cs0 = (int)cv.x, cs1 = (int)cv.y, cs2 = (int)cv.z, cs3 = (int)cv.w;

    if (((rs0 | rs1 | rs2 | rs3) | (cs0 | cs1 | cs2 | cs3)) == 0) {
        // identity placement; nt store keeps out of L2/L3 (out is never read)
        __builtin_nontemporal_store(xv, reinterpret_cast<vf4*>(out + base));
    } else {
        vf4 ov;
        ov.x = ((rs0 | cs0) == 0) ? xv.x : 0.0f;
        ov.y = ((rs1 | cs1) == 0) ? xv.y : 0.0f;
        ov.z = ((rs2 | cs2) == 0) ? xv.z : 0.0f;
        ov.w = ((rs3 | cs3) == 0) ? xv.w : 0.0f;
        __builtin_nontemporal_store(ov, reinterpret_cast<vf4*>(out + base));
        unsigned slot = atomicAdd(ws_count, 1u);    // device-scope by default
        ws_list[slot] = (unsigned)tid;
    }
}

__global__ __launch_bounds__(256) void worklist_scatter_kernel(
    const float* __restrict__ x,
    const float* __restrict__ wr,
    const float* __restrict__ wc,
    float* __restrict__ out,
    const unsigned* __restrict__ ws_count,
    const unsigned* __restrict__ ws_list)
{
    const unsigned count  = ws_count[0];
    const unsigned stride = gridDim.x * blockDim.x;
    for (unsigned i = blockIdx.x * blockDim.x + threadIdx.x; i < count; i += stride) {
        long long base = (long long)ws_list[i] * 4;
        int row = (int)(base >> 13);
        int col = (int)(base & (W - 1));

        const vf4 xv = *reinterpret_cast<const vf4*>(x  + base);
        const vf4 rv = *reinterpret_cast<const vf4*>(wr + base);
        const vf4 cv = *reinterpret_cast<const vf4*>(wc + base);

        int rs, cs, tr, tc;
        rs = (int)rv.x; cs = (int)cv.x;
        if ((rs | cs) != 0) { tr = row + rs; tc = col + 0 + cs;
            if ((unsigned)tr < (unsigned)H && (unsigned)tc < (unsigned)W)
                out[(long long)tr * W + tc] = xv.x; }
        rs = (int)rv.y; cs = (int)cv.y;
        if ((rs | cs) != 0) { tr = row + rs; tc = col + 1 + cs;
            if ((unsigned)tr < (unsigned)H && (unsigned)tc < (unsigned)W)
                out[(long long)tr * W + tc] = xv.y; }
        rs = (int)rv.z; cs = (int)cv.z;
        if ((rs | cs) != 0) { tr = row + rs; tc = col + 2 + cs;
            if ((unsigned)tr < (unsigned)H && (unsigned)tc < (unsigned)W)
                out[(long long)tr * W + tc] = xv.z; }
        rs = (int)rv.w; cs = (int)cv.w;
        if ((rs | cs) != 0) { tr = row + rs; tc = col + 3 + cs;
            if ((unsigned)tr < (unsigned)H && (unsigned)tc < (unsigned)W)
                out[(long long)tr * W + tc] = xv.w; }
    }
}

// ---- fallback path (if d_ws too small): zero + full scatter --------------

__global__ __launch_bounds__(256) void zero_out_kernel(float* __restrict__ out) {
    long long tid = (long long)blockIdx.x * blockDim.x + threadIdx.x;
    vf4 z = {0.f, 0.f, 0.f, 0.f};
    __builtin_nontemporal_store(z, reinterpret_cast<vf4*>(out + tid * 4));
}

__global__ __launch_bounds__(256) void shift_scatter_kernel(
    const float* __restrict__ x,
    const float* __restrict__ wr,
    const float* __restrict__ wc,
    float* __restrict__ out)
{
    long long tid  = (long long)blockIdx.x * blockDim.x + threadIdx.x;
    long long base = tid * 4;
    int row = (int)(base >> 13);
    int col = (int)(base & (W - 1));

    const vf4 xv = *reinterpret_cast<const vf4*>(x  + base);
    const vf4 rv = *reinterpret_cast<const vf4*>(wr + base);
    const vf4 cv = *reinterpret_cast<const vf4*>(wc + base);

    int rs0 = (int)rv.x, rs1 = (int)rv.y, rs2 = (int)rv.z, rs3 = (int)rv.w;
    int cs0 = (int)cv.x, cs1 = (int)cv.y, cs2 = (int)cv.z, cs3 = (int)cv.w;

    if (((rs0 | rs1 | rs2 | rs3) | (cs0 | cs1 | cs2 | cs3)) == 0) {
        __builtin_nontemporal_store(xv, reinterpret_cast<vf4*>(out + base));
        return;
    }
    int tr, tc;
    tr = row + rs0; tc = col + 0 + cs0;
    if ((unsigned)tr < (unsigned)H && (unsigned)tc < (unsigned)W)
        out[(long long)tr * W + tc] = xv.x;
    tr = row + rs1; tc = col + 1 + cs1;
    if ((unsigned)tr < (unsigned)H && (unsigned)tc < (unsigned)W)
        out[(long long)tr * W + tc] = xv.y;
    tr = row + rs2; tc = col + 2 + cs2;
    if ((unsigned)tr < (unsigned)H && (unsigned)tc < (unsigned)W)
        out[(long long)tr * W + tc] = xv.z;
    tr = row + rs3; tc = col + 3 + cs3;
    if ((unsigned)tr < (unsigned)H && (unsigned)tc < (unsigned)W)
        out[(long long)tr * W + tc] = xv.w;
}

// ---- launch --------------------------------------------------------------

extern "C" void kernel_launch(void* const* d_in, const int* in_sizes, int n_in,
                              void* d_out, int out_size, void* d_ws, size_t ws_size,
                              hipStream_t stream) {
    const float* x  = (const float*)d_in[0];
    const float* wr = (const float*)d_in[1];
    const float* wc = (const float*)d_in[2];
    float* out = (float*)d_out;

    const int block = 256;
    const int grid  = (int)(NCHUNK / block);            // 32,768 blocks

    // worklist layout in d_ws: [0] counter (unsigned), [16..] chunk indices
    const size_t ws_needed = 16 + (size_t)NCHUNK * sizeof(unsigned);

    if (ws_size >= ws_needed) {
        unsigned* ws_count = (unsigned*)d_ws;
        unsigned* ws_list  = (unsigned*)((char*)d_ws + 16);
        init_ws_kernel<<<1, 64, 0, stream>>>(ws_count);
        fused_place_kernel<<<grid, block, 0, stream>>>(x, wr, wc, out,
                                                       ws_count, ws_list);
        worklist_scatter_kernel<<<2048, block, 0, stream>>>(x, wr, wc, out,
                                                            ws_count, ws_list);
    } else {
        zero_out_kernel<<<grid, block, 0, stream>>>(out);
        shift_scatter_kernel<<<grid, block, 0, stream>>>(x, wr, wc, out);
    }
}

// Round 5
// 382.931 us; speedup vs baseline: 1.0289x; 1.0258x over previous
//
#include <hip/hip_runtime.h>

// ShiftingLayer: out = zeros(H,W); out[i + trunc(wr[i,j]), j + trunc(wc[i,j])] = x[i,j]
// (OOB targets dropped). H=4096, W=8192, fp32.
//
// Pass A (fused_place): each thread owns 4 float4 chunks (grid-stride-by-
//   blockDim layout, all 12 loads issued before use for MLP). At its own
//   location it writes x where the element's shift is zero, 0 where it
//   isn't; chunks with any nonzero shift go to a worklist in d_ws.
// Pass B (worklist_scatter): scatters only nonzero-shift elements (empty
//   for the bench inputs -> exits immediately).
//
// R4 lesson: __builtin_nontemporal_store regressed streaming stores ~10%
// (131 -> 146 us at identical traffic) — use plain stores.

constexpr int H = 4096;
constexpr int W = 8192;                         // 2^13
constexpr long long TOTAL  = (long long)H * W;  // 33,554,432
constexpr long long NCHUNK = TOTAL / 4;         // 8,388,608 float4 chunks
constexpr int BLOCK = 256;
constexpr int CPT   = 4;                        // chunks per thread

typedef float vf4 __attribute__((ext_vector_type(4)));

// ---- worklist path -------------------------------------------------------

__global__ __launch_bounds__(64) void init_ws_kernel(unsigned* __restrict__ ws) {
    if (threadIdx.x == 0) ws[0] = 0u;           // d_ws is poisoned 0xAA each call
}

__global__ __launch_bounds__(BLOCK) void fused_place_kernel(
    const float* __restrict__ x,
    const float* __restrict__ wr,
    const float* __restrict__ wc,
    float* __restrict__ out,
    unsigned* __restrict__ ws_count,
    unsigned* __restrict__ ws_list)
{
    const long long chunk0 = (long long)blockIdx.x * (BLOCK * CPT) + threadIdx.x;

    vf4 xv[CPT], rv[CPT], cv[CPT];
    #pragma unroll
    for (int u = 0; u < CPT; ++u) {
        const long long base = (chunk0 + (long long)u * BLOCK) * 4;
        xv[u] = *reinterpret_cast<const vf4*>(x  + base);
        rv[u] = *reinterpret_cast<const vf4*>(wr + base);
        cv[u] = *reinterpret_cast<const vf4*>(wc + base);
    }

    #pragma unroll
    for (int u = 0; u < CPT; ++u) {
        const long long chunk = chunk0 + (long long)u * BLOCK;
        const long long base  = chunk * 4;

        // C float->int cast truncates toward zero == jnp.trunc + astype(int32)
        int rs0 = (int)rv[u].x, rs1 = (int)rv[u].y,
            rs2 = (int)rv[u].z, rs3 = (int)rv[u].w;
        int cs0 = (int)cv[u].x, cs1 = (int)cv[u].y,
            cs2 = (int)cv[u].z, cs3 = (int)cv[u].w;

        if (((rs0 | rs1 | rs2 | rs3) | (cs0 | cs1 | cs2 | cs3)) == 0) {
            *reinterpret_cast<vf4*>(out + base) = xv[u];
        } else {
            vf4 ov;
            ov.x = ((rs0 | cs0) == 0) ? xv[u].x : 0.0f;
            ov.y = ((rs1 | cs1) == 0) ? xv[u].y : 0.0f;
            ov.z = ((rs2 | cs2) == 0) ? xv[u].z : 0.0f;
            ov.w = ((rs3 | cs3) == 0) ? xv[u].w : 0.0f;
            *reinterpret_cast<vf4*>(out + base) = ov;
            unsigned slot = atomicAdd(ws_count, 1u);   // device-scope default
            ws_list[slot] = (unsigned)chunk;
        }
    }
}

__global__ __launch_bounds__(BLOCK) void worklist_scatter_kernel(
    const float* __restrict__ x,
    const float* __restrict__ wr,
    const float* __restrict__ wc,
    float* __restrict__ out,
    const unsigned* __restrict__ ws_count,
    const unsigned* __restrict__ ws_list)
{
    const unsigned count  = ws_count[0];
    const unsigned stride = gridDim.x * blockDim.x;
    for (unsigned i = blockIdx.x * blockDim.x + threadIdx.x; i < count; i += stride) {
        long long base = (long long)ws_list[i] * 4;
        int row = (int)(base >> 13);
        int col = (int)(base & (W - 1));

        const vf4 xv = *reinterpret_cast<const vf4*>(x  + base);
        const vf4 rv = *reinterpret_cast<const vf4*>(wr + base);
        const vf4 cv = *reinterpret_cast<const vf4*>(wc + base);

        int rs, cs, tr, tc;
        rs = (int)rv.x; cs = (int)cv.x;
        if ((rs | cs) != 0) { tr = row + rs; tc = col + 0 + cs;
            if ((unsigned)tr < (unsigned)H && (unsigned)tc < (unsigned)W)
                out[(long long)tr * W + tc] = xv.x; }
        rs = (int)rv.y; cs = (int)cv.y;
        if ((rs | cs) != 0) { tr = row + rs; tc = col + 1 + cs;
            if ((unsigned)tr < (unsigned)H && (unsigned)tc < (unsigned)W)
                out[(long long)tr * W + tc] = xv.y; }
        rs = (int)rv.z; cs = (int)cv.z;
        if ((rs | cs) != 0) { tr = row + rs; tc = col + 2 + cs;
            if ((unsigned)tr < (unsigned)H && (unsigned)tc < (unsigned)W)
                out[(long long)tr * W + tc] = xv.z; }
        rs = (int)rv.w; cs = (int)cv.w;
        if ((rs | cs) != 0) { tr = row + rs; tc = col + 3 + cs;
            if ((unsigned)tr < (unsigned)H && (unsigned)tc < (unsigned)W)
                out[(long long)tr * W + tc] = xv.w; }
    }
}

// ---- fallback path (if d_ws too small): zero + full scatter --------------

__global__ __launch_bounds__(BLOCK) void zero_out_kernel(float* __restrict__ out) {
    long long tid = (long long)blockIdx.x * blockDim.x + threadIdx.x;
    vf4 z = {0.f, 0.f, 0.f, 0.f};
    *reinterpret_cast<vf4*>(out + tid * 4) = z;
}

__global__ __launch_bounds__(BLOCK) void shift_scatter_kernel(
    const float* __restrict__ x,
    const float* __restrict__ wr,
    const float* __restrict__ wc,
    float* __restrict__ out)
{
    long long tid  = (long long)blockIdx.x * blockDim.x + threadIdx.x;
    long long base = tid * 4;
    int row = (int)(base >> 13);
    int col = (int)(base & (W - 1));

    const vf4 xv = *reinterpret_cast<const vf4*>(x  + base);
    const vf4 rv = *reinterpret_cast<const vf4*>(wr + base);
    const vf4 cv = *reinterpret_cast<const vf4*>(wc + base);

    int rs0 = (int)rv.x, rs1 = (int)rv.y, rs2 = (int)rv.z, rs3 = (int)rv.w;
    int cs0 = (int)cv.x, cs1 = (int)cv.y, cs2 = (int)cv.z, cs3 = (int)cv.w;

    if (((rs0 | rs1 | rs2 | rs3) | (cs0 | cs1 | cs2 | cs3)) == 0) {
        *reinterpret_cast<vf4*>(out + base) = xv;
        return;
    }
    int tr, tc;
    tr = row + rs0; tc = col + 0 + cs0;
    if ((unsigned)tr < (unsigned)H && (unsigned)tc < (unsigned)W)
        out[(long long)tr * W + tc] = xv.x;
    tr = row + rs1; tc = col + 1 + cs1;
    if ((unsigned)tr < (unsigned)H && (unsigned)tc < (unsigned)W)
        out[(long long)tr * W + tc] = xv.y;
    tr = row + rs2; tc = col + 2 + cs2;
    if ((unsigned)tr < (unsigned)H && (unsigned)tc < (unsigned)W)
        out[(long long)tr * W + tc] = xv.z;
    tr = row + rs3; tc = col + 3 + cs3;
    if ((unsigned)tr < (unsigned)H && (unsigned)tc < (unsigned)W)
        out[(long long)tr * W + tc] = xv.w;
}

// ---- launch --------------------------------------------------------------

extern "C" void kernel_launch(void* const* d_in, const int* in_sizes, int n_in,
                              void* d_out, int out_size, void* d_ws, size_t ws_size,
                              hipStream_t stream) {
    const float* x  = (const float*)d_in[0];
    const float* wr = (const float*)d_in[1];
    const float* wc = (const float*)d_in[2];
    float* out = (float*)d_out;

    // worklist layout in d_ws: [0] counter (unsigned), [16..] chunk indices
    const size_t ws_needed = 16 + (size_t)NCHUNK * sizeof(unsigned);

    if (ws_size >= ws_needed) {
        unsigned* ws_count = (unsigned*)d_ws;
        unsigned* ws_list  = (unsigned*)((char*)d_ws + 16);
        const int grid = (int)(NCHUNK / (BLOCK * CPT));     // 8192 blocks
        init_ws_kernel<<<1, 64, 0, stream>>>(ws_count);
        fused_place_kernel<<<grid, BLOCK, 0, stream>>>(x, wr, wc, out,
                                                       ws_count, ws_list);
        worklist_scatter_kernel<<<1024, BLOCK, 0, stream>>>(x, wr, wc, out,
                                                            ws_count, ws_list);
    } else {
        const int grid = (int)(NCHUNK / BLOCK);             // 32768 blocks
        zero_out_kernel<<<grid, BLOCK, 0, stream>>>(out);
        shift_scatter_kernel<<<grid, BLOCK, 0, stream>>>(x, wr, wc, out);
    }
}